// Round 1
// baseline (269.891 us; speedup 1.0000x reference)
//
#include <hip/hip_runtime.h>
#include <stdint.h>

#define LDS_AS __attribute__((address_space(3)))
#define GLB_AS __attribute__((address_space(1)))

typedef unsigned short bfu;                                   // bf16 bit pattern
typedef __attribute__((ext_vector_type(8))) short short8;     // MFMA A/B frag (8 bf16)
typedef __attribute__((ext_vector_type(4))) float f32x4;      // MFMA C/D frag

static constexpr int B_  = 8192;
static constexpr int D_  = 1024;
static constexpr int E_  = 16;
static constexpr int H_  = 256;
static constexpr int EH_ = E_ * H_;     // 4096
static constexpr int KE_ = EH_ + 64;    // 4160 : +16 route cols (for b2) +48 zeros

__device__ __forceinline__ bfu f2b(float f) {
  unsigned u = __float_as_uint(f);
  u = (u + 0x7FFFu + ((u >> 16) & 1u)) >> 16;   // RNE, finite data
  return (bfu)u;
}

__device__ __forceinline__ void gload_lds16(const bfu* g, bfu* l) {
  __builtin_amdgcn_global_load_lds((const GLB_AS void*)g, (LDS_AS void*)l, 16, 0, 0);
}

// ---------------- converts ----------------
__global__ void k_f32_to_bf16(const float* __restrict__ in, bfu* __restrict__ out, int n4) {
  int i = blockIdx.x * 256 + threadIdx.x;
  if (i >= n4) return;
  float4 v = reinterpret_cast<const float4*>(in)[i];
  ushort4 o;
  o.x = f2b(v.x); o.y = f2b(v.y); o.z = f2b(v.z); o.w = f2b(v.w);
  reinterpret_cast<ushort4*>(out)[i] = o;
}

// W2 [E][D][H] f32 -> W2t [D][KE_] bf16 with W2t[d][e*256+h] = W2[e][d][h]
__global__ void k_w2_transpose(const float* __restrict__ W2, bfu* __restrict__ W2t) {
  int i = blockIdx.x * 256 + threadIdx.x;   // [0, 16*1024*64)
  if (i >= E_ * D_ * (H_ / 4)) return;
  int h4 = i & 63;
  int d  = (i >> 6) & (D_ - 1);
  int e  = i >> 16;
  float4 v = reinterpret_cast<const float4*>(W2)[((e << 10) | d) * 64 + h4];
  ushort4 o;
  o.x = f2b(v.x); o.y = f2b(v.y); o.z = f2b(v.z); o.w = f2b(v.w);
  reinterpret_cast<ushort4*>(W2t + (size_t)d * KE_ + (e << 8))[h4] = o;
}

// extension rows of W2t: cols 4096..4111 <- b2[e][d], 4112..4159 <- 0
__global__ void k_w2t_ext(const float* __restrict__ b2, bfu* __restrict__ W2t) {
  int i = blockIdx.x * 256 + threadIdx.x;   // [0, 1024*64)
  if (i >= D_ * 64) return;
  int j = i & 63, d = i >> 6;
  float v = (j < E_) ? b2[(size_t)j * D_ + d] : 0.f;
  W2t[(size_t)d * KE_ + EH_ + j] = f2b(v);
}

// extension cols of H': route (bf16) then zeros
__global__ void k_h_ext(const float* __restrict__ route, bfu* __restrict__ Hp,
                        int row0, int rows) {
  int i = blockIdx.x * 256 + threadIdx.x;
  if (i >= rows * 64) return;
  int j = i & 63, r = i >> 6;
  float v = (j < E_) ? route[(size_t)(row0 + r) * E_ + j] : 0.f;
  Hp[(size_t)r * KE_ + EH_ + j] = f2b(v);
}

// ---------------- router (fp32, exact) ----------------
__global__ __launch_bounds__(256)
void k_router(const float* __restrict__ cond, const float* __restrict__ Wr1,
              const float* __restrict__ br1, const float* __restrict__ Wr2,
              const float* __restrict__ br2, float* __restrict__ route) {
  __shared__ float sW1[128][65];   // pad -> (j + c) % 32 banks, 2-way max (free)
  __shared__ float sW2[16][129];
  __shared__ float sb1[128], sb2[16];
  __shared__ float sc[2][64];
  __shared__ float srh[2][128];
  const int t = threadIdx.x;
  for (int i = t; i < 128 * 64; i += 256) sW1[i >> 6][i & 63] = Wr1[i];
  for (int i = t; i < 16 * 128; i += 256) sW2[i >> 7][i & 127] = Wr2[i];
  if (t < 128) sb1[t] = br1[t];
  else if (t < 144) sb2[t - 128] = br2[t - 128];
  const int rowBase = blockIdx.x * 32;
  for (int r0 = 0; r0 < 32; r0 += 2) {
    __syncthreads();
    if (t < 128) sc[t >> 6][t & 63] = cond[(size_t)(rowBase + r0 + (t >> 6)) * 64 + (t & 63)];
    __syncthreads();
    {
      const int half = t >> 7, j = t & 127;
      float a = sb1[j];
      #pragma unroll 16
      for (int c = 0; c < 64; ++c) a = fmaf(sc[half][c], sW1[j][c], a);
      srh[half][j] = fmaxf(a, 0.f);
    }
    __syncthreads();
    if (t < 32) {
      const int half = t >> 4, e = t & 15;
      float a = sb2[e];
      #pragma unroll 16
      for (int k = 0; k < 128; ++k) a = fmaf(srh[half][k], sW2[e][k], a);
      float mx = a;
      #pragma unroll
      for (int m = 8; m; m >>= 1) mx = fmaxf(mx, __shfl_xor(mx, m, 16));
      float p = __expf(a - mx);
      float s = p;
      #pragma unroll
      for (int m = 8; m; m >>= 1) s += __shfl_xor(s, m, 16);
      route[(size_t)(rowBase + r0 + half) * 16 + e] = p / s;
    }
  }
}

// ---------------- GEMM-BT: C[M,N] = A[M,K] * B[N,K]^T  (m97 structure) ----------------
// EPI=1: v = relu(acc + b1[col]) * route[row,e(col)] -> bf16 H'  (GEMM1)
// EPI=2: f32 store                                                 (GEMM2)
template <int EPI>
__global__ __launch_bounds__(256)
void k_gemm_bt(const bfu* __restrict__ A, int lda,
               const bfu* __restrict__ Bm, int ldb,
               int K, int ntc,
               float* __restrict__ outF, bfu* __restrict__ outB, int ldc,
               const float* __restrict__ route, const float* __restrict__ bias1,
               int row0g) {
  __shared__ __align__(16) bfu sA[128 * 64];
  __shared__ __align__(16) bfu sB[128 * 64];
  const int t = (int)threadIdx.x;
  const int w = t >> 6, l = t & 63;
  const int wr = w >> 1, wc = w & 1;

  // XCD-contiguous swizzle (grid always divisible by 8 here)
  const int nwg = (int)gridDim.x;
  const int bid = (int)blockIdx.x;
  const int swz = (bid & 7) * (nwg >> 3) + (bid >> 3);
  const int brow = (swz / ntc) * 128;
  const int bcol = (swz % ntc) * 128;

  f32x4 acc[4][4] = {};

  const int lr = l >> 3;           // staging: row within 8-row chunk
  const int lc = (l & 7) * 8;      // staging: col element
  const int nk = K >> 6;
  for (int kt = 0; kt < nk; ++kt) {
    const int k0 = kt << 6;
    #pragma unroll
    for (int i = 0; i < 4; ++i) {
      const int chunk = w * 4 + i;              // 16 chunks x 8 rows = 128 rows
      const int row = chunk * 8 + lr;
      gload_lds16(A  + (size_t)(brow + row) * lda + (k0 + lc), &sA[(chunk * 64 + l) * 8]);
      gload_lds16(Bm + (size_t)(bcol + row) * ldb + (k0 + lc), &sB[(chunk * 64 + l) * 8]);
    }
    __syncthreads();   // compiler drains vmcnt before s_barrier
    #pragma unroll
    for (int kk = 0; kk < 2; ++kk) {
      short8 af[4], bfv[4];
      #pragma unroll
      for (int m = 0; m < 4; ++m)
        af[m] = *reinterpret_cast<const short8*>(
            &sA[(wr * 64 + m * 16 + (l & 15)) * 64 + kk * 32 + (l >> 4) * 8]);
      #pragma unroll
      for (int n = 0; n < 4; ++n)
        bfv[n] = *reinterpret_cast<const short8*>(
            &sB[(wc * 64 + n * 16 + (l & 15)) * 64 + kk * 32 + (l >> 4) * 8]);
      #pragma unroll
      for (int m = 0; m < 4; ++m)
        #pragma unroll
        for (int n = 0; n < 4; ++n)
          acc[m][n] = __builtin_amdgcn_mfma_f32_16x16x32_bf16(af[m], bfv[n], acc[m][n], 0, 0, 0);
    }
    __syncthreads();
  }

  const int fr = l & 15, fq = l >> 4;
  if (EPI == 1) {
    const int e = bcol >> 8;   // 128-wide tile lies inside one 256-wide expert block
    #pragma unroll
    for (int m = 0; m < 4; ++m) {
      const int rl = brow + wr * 64 + m * 16 + fq * 4;
      float rt[4];
      #pragma unroll
      for (int j = 0; j < 4; ++j) rt[j] = route[(size_t)(row0g + rl + j) * E_ + e];
      #pragma unroll
      for (int n = 0; n < 4; ++n) {
        const int col = bcol + wc * 64 + n * 16 + fr;
        const float bz = bias1[col];
        #pragma unroll
        for (int j = 0; j < 4; ++j) {
          float v = fmaxf(acc[m][n][j] + bz, 0.f) * rt[j];
          outB[(size_t)(rl + j) * ldc + col] = f2b(v);
        }
      }
    }
  } else {
    #pragma unroll
    for (int m = 0; m < 4; ++m) {
      const int rl = brow + wr * 64 + m * 16 + fq * 4;
      #pragma unroll
      for (int n = 0; n < 4; ++n) {
        const int col = bcol + wc * 64 + n * 16 + fr;
        #pragma unroll
        for (int j = 0; j < 4; ++j)
          outF[(size_t)(rl + j) * ldc + col] = acc[m][n][j];
      }
    }
  }
}

// ---------------- launch ----------------
extern "C" void kernel_launch(void* const* d_in, const int* in_sizes, int n_in,
                              void* d_out, int out_size, void* d_ws, size_t ws_size,
                              hipStream_t stream) {
  const float* x    = (const float*)d_in[0];
  const float* cond = (const float*)d_in[1];
  const float* W1   = (const float*)d_in[2];
  const float* b1   = (const float*)d_in[3];
  const float* W2   = (const float*)d_in[4];
  const float* b2   = (const float*)d_in[5];
  const float* Wr1  = (const float*)d_in[6];
  const float* br1  = (const float*)d_in[7];
  const float* Wr2  = (const float*)d_in[8];
  const float* br2  = (const float*)d_in[9];
  float* out = (float*)d_out;

  char* p = (char*)d_ws;
  auto alloc = [&](size_t bytes) {
    char* q = p;
    p += (bytes + 255) & ~(size_t)255;
    return q;
  };
  bfu*   xb    = (bfu*)  alloc((size_t)B_ * D_ * 2);    // 16 MB
  bfu*   W1b   = (bfu*)  alloc((size_t)EH_ * D_ * 2);   //  8 MB
  bfu*   W2t   = (bfu*)  alloc((size_t)D_ * KE_ * 2);   //  8.5 MB
  float* route = (float*)alloc((size_t)B_ * E_ * 4);    //  0.5 MB
  size_t used = (size_t)(p - (char*)d_ws);
  size_t rem  = ws_size > used ? ws_size - used : 0;
  long maxRows = (long)(rem / ((size_t)KE_ * 2));
  int CB = (int)((maxRows / 128) * 128);
  if (CB > B_) CB = B_;
  if (CB < 128) CB = 128;                                // assume ws is sufficient
  bfu* Hp = (bfu*)p;                                     // CB x 4160 bf16

  k_f32_to_bf16<<<(B_ * D_ / 4 + 255) / 256, 256, 0, stream>>>(x, xb, B_ * D_ / 4);
  k_f32_to_bf16<<<(EH_ * D_ / 4 + 255) / 256, 256, 0, stream>>>(W1, W1b, EH_ * D_ / 4);
  k_w2_transpose<<<(E_ * D_ * (H_ / 4) + 255) / 256, 256, 0, stream>>>(W2, W2t);
  k_w2t_ext<<<(D_ * 64 + 255) / 256, 256, 0, stream>>>(b2, W2t);
  k_router<<<B_ / 32, 256, 0, stream>>>(cond, Wr1, br1, Wr2, br2, route);

  for (int r0 = 0; r0 < B_; r0 += CB) {
    int rows = (B_ - r0 < CB) ? (B_ - r0) : CB;
    k_h_ext<<<(rows * 64 + 255) / 256, 256, 0, stream>>>(route, Hp, r0, rows);
    // GEMM1: H'[rows, 4096] = relu(xb[rows,1024] @ W1b[4096,1024]^T + b1) * route
    k_gemm_bt<1><<<dim3((rows / 128) * (EH_ / 128)), 256, 0, stream>>>(
        xb + (size_t)r0 * D_, D_, W1b, D_, D_, EH_ / 128,
        nullptr, Hp, KE_, route, b1, r0);
    // GEMM2: out[rows,1024] = H'[rows,4160] @ W2t[1024,4160]^T   (b2 via K-extension)
    k_gemm_bt<2><<<dim3((rows / 128) * (D_ / 128)), 256, 0, stream>>>(
        Hp, KE_, W2t, KE_, KE_, D_ / 128,
        out + (size_t)r0 * D_, nullptr, D_, nullptr, nullptr, 0);
  }
}

// Round 2
// 248.829 us; speedup vs baseline: 1.0846x; 1.0846x over previous
//
#include <hip/hip_runtime.h>
#include <stdint.h>

#define LDS_AS __attribute__((address_space(3)))
#define GLB_AS __attribute__((address_space(1)))

typedef unsigned short bfu;                                   // bf16 bit pattern
typedef __attribute__((ext_vector_type(8))) short short8;     // MFMA A/B frag (8 bf16)
typedef __attribute__((ext_vector_type(4))) float f32x4;      // MFMA C/D frag

static constexpr int B_  = 8192;
static constexpr int D_  = 1024;
static constexpr int E_  = 16;
static constexpr int H_  = 256;
static constexpr int EH_ = E_ * H_;     // 4096

__device__ __forceinline__ bfu f2b(float f) {
  unsigned u = __float_as_uint(f);
  u = (u + 0x7FFFu + ((u >> 16) & 1u)) >> 16;   // RNE, finite data
  return (bfu)u;
}
__device__ __forceinline__ float b2f(bfu b) {
  return __uint_as_float(((unsigned)b) << 16);
}

__device__ __forceinline__ void gload_lds16(const bfu* g, bfu* l) {
  __builtin_amdgcn_global_load_lds((const GLB_AS void*)g, (LDS_AS void*)l, 16, 0, 0);
}

// ---------------- converts ----------------
__global__ void k_f32_to_bf16(const float* __restrict__ in, bfu* __restrict__ out, int n4) {
  int i = blockIdx.x * 256 + threadIdx.x;
  if (i >= n4) return;
  float4 v = reinterpret_cast<const float4*>(in)[i];
  ushort4 o;
  o.x = f2b(v.x); o.y = f2b(v.y); o.z = f2b(v.z); o.w = f2b(v.w);
  reinterpret_cast<ushort4*>(out)[i] = o;
}

// W2 [E][D][H] f32 -> W2t [D][EH_] bf16 with W2t[d][e*256+h] = W2[e][d][h]
__global__ void k_w2_transpose(const float* __restrict__ W2, bfu* __restrict__ W2t) {
  int i = blockIdx.x * 256 + threadIdx.x;   // [0, 16*1024*64)
  if (i >= E_ * D_ * (H_ / 4)) return;
  int h4 = i & 63;
  int d  = (i >> 6) & (D_ - 1);
  int e  = i >> 16;
  float4 v = reinterpret_cast<const float4*>(W2)[((e << 10) | d) * 64 + h4];
  ushort4 o;
  o.x = f2b(v.x); o.y = f2b(v.y); o.z = f2b(v.z); o.w = f2b(v.w);
  reinterpret_cast<ushort4*>(W2t + ((size_t)d << 12) + (e << 8))[h4] = o;
}

// ---------------- router (fp32, exact) ----------------
__global__ __launch_bounds__(256)
void k_router(const float* __restrict__ cond, const float* __restrict__ Wr1,
              const float* __restrict__ br1, const float* __restrict__ Wr2,
              const float* __restrict__ br2, float* __restrict__ route) {
  __shared__ float sW1[128][65];
  __shared__ float sW2[16][129];
  __shared__ float sb1[128], sb2[16];
  __shared__ float sc[2][64];
  __shared__ float srh[2][128];
  const int t = threadIdx.x;
  for (int i = t; i < 128 * 64; i += 256) sW1[i >> 6][i & 63] = Wr1[i];
  for (int i = t; i < 16 * 128; i += 256) sW2[i >> 7][i & 127] = Wr2[i];
  if (t < 128) sb1[t] = br1[t];
  else if (t < 144) sb2[t - 128] = br2[t - 128];
  const int rowBase = blockIdx.x * 32;
  for (int r0 = 0; r0 < 32; r0 += 2) {
    __syncthreads();
    if (t < 128) sc[t >> 6][t & 63] = cond[(size_t)(rowBase + r0 + (t >> 6)) * 64 + (t & 63)];
    __syncthreads();
    {
      const int half = t >> 7, j = t & 127;
      float a = sb1[j];
      #pragma unroll 16
      for (int c = 0; c < 64; ++c) a = fmaf(sc[half][c], sW1[j][c], a);
      srh[half][j] = fmaxf(a, 0.f);
    }
    __syncthreads();
    if (t < 32) {
      const int half = t >> 4, e = t & 15;
      float a = sb2[e];
      #pragma unroll 16
      for (int k = 0; k < 128; ++k) a = fmaf(srh[half][k], sW2[e][k], a);
      float mx = a;
      #pragma unroll
      for (int m = 8; m; m >>= 1) mx = fmaxf(mx, __shfl_xor(mx, m, 16));
      float p = __expf(a - mx);
      float s = p;
      #pragma unroll
      for (int m = 8; m; m >>= 1) s += __shfl_xor(s, m, 16);
      route[(size_t)(rowBase + r0 + half) * 16 + e] = p / s;
    }
  }
}

// ---------------- 256x256 8-phase GEMM-BT (T2+T3+T4+T5) ----------------
// C[M,N] = A[M,K] * B[N,K]^T. 8 waves (2M x 4N), BK=64, LDS 128KB (2 buf).
// EPI=1: bf16 store of relu(acc+b1[col])*route[row,e]   (GEMM1 -> Hp)
// EPI=2: split-K x2; chunk0 -> f32 out, chunk1 -> bf16 partial (GEMM2)

#define PH_BARRIER() __builtin_amdgcn_s_barrier()
#define WAIT_LGKM0() do { asm volatile("s_waitcnt lgkmcnt(0)" ::: "memory"); \
                          __builtin_amdgcn_sched_barrier(0); } while (0)
#define WAIT_VM4()   do { asm volatile("s_waitcnt vmcnt(4)" ::: "memory"); } while (0)

// stage one 128x64 half-tile: linear LDS dest, inverse-swizzled global source.
#define STAGE(matPtr, ld_, rowTile0, half_, tile_, buf_, isA_)                    \
  do {                                                                            \
    int kt_ = (tile_); if (kt_ >= nkt) kt_ -= nkt;                                \
    const int kel_ = kOff + (kt_ << 6);                                           \
    bfu* dst_ = lds + ((((buf_) << 2) | ((isA_) ? 0 : 2) | (half_)) << 13);       \
    _Pragma("unroll")                                                             \
    for (int j_ = 0; j_ < 2; ++j_) {                                              \
      int c_ = (j_ << 9) | tid;                                                   \
      int r_ = c_ >> 3;                                                           \
      int sb_ = (((c_ & 7) << 4) ^ ((r_ & 7) << 4));                              \
      gload_lds16((matPtr) + (size_t)((rowTile0) + ((half_) << 7) + r_) * (ld_)   \
                      + kel_ + (sb_ >> 1),                                        \
                  dst_ + c_ * 8);                                                 \
    }                                                                             \
  } while (0)

#define LDA_FRAG(dst_, buf_, m_, kk_)                                             \
  dst_ = *reinterpret_cast<const short8*>(                                        \
      reinterpret_cast<const char*>(lds + ((((buf_) << 2) | wr) << 13)) +         \
      ((((m_) << 11) + ((kk_) << 6) + aBaseByte) ^ axor))

#define LDB_FRAG(dst_, buf_, n_, kk_)                                             \
  dst_ = *reinterpret_cast<const short8*>(                                        \
      reinterpret_cast<const char*>(lds + ((((buf_) << 2) | 2 | bhalfSel) << 13)) + \
      ((bInner + (((n_) << 11) + ((kk_) << 6) + aBaseByte)) ^ axor))

#define MFMA_Q(AF_, BF_, mg_, ng_)                                                \
  _Pragma("unroll") for (int mm_ = 0; mm_ < 4; ++mm_)                             \
  _Pragma("unroll") for (int nn_ = 0; nn_ < 2; ++nn_)                             \
  _Pragma("unroll") for (int k2_ = 0; k2_ < 2; ++k2_)                             \
    acc[(mg_) * 4 + mm_][(ng_) * 2 + nn_] =                                       \
        __builtin_amdgcn_mfma_f32_16x16x32_bf16(                                  \
            AF_[mm_][k2_], BF_[nn_][k2_],                                         \
            acc[(mg_) * 4 + mm_][(ng_) * 2 + nn_], 0, 0, 0);

#define TILE_STEP(T_, c_)                                                         \
  do {                                                                            \
    /* P1: A m0-3 + B n0-1 reads; prefetch B-half1(T+1)->buf^1 */                 \
    _Pragma("unroll") for (int m_ = 0; m_ < 4; ++m_)                              \
      _Pragma("unroll") for (int k2_ = 0; k2_ < 2; ++k2_)                         \
        LDA_FRAG(a_[m_][k2_], (c_), m_, k2_);                                     \
    _Pragma("unroll") for (int n_ = 0; n_ < 2; ++n_)                              \
      _Pragma("unroll") for (int k2_ = 0; k2_ < 2; ++k2_)                         \
        LDB_FRAG(b0_[n_][k2_], (c_), n_, k2_);                                    \
    STAGE(Bm, ldb, bcol, 1, (T_) + 1, (c_) ^ 1, 0);                               \
    PH_BARRIER(); WAIT_LGKM0();                                                   \
    __builtin_amdgcn_s_setprio(1);                                                \
    MFMA_Q(a_, b0_, 0, 0);                                                        \
    __builtin_amdgcn_s_setprio(0); PH_BARRIER();                                  \
    /* P2: B n2-3 reads; prefetch A-half1(T+1)->buf^1 */                          \
    _Pragma("unroll") for (int n_ = 0; n_ < 2; ++n_)                              \
      _Pragma("unroll") for (int k2_ = 0; k2_ < 2; ++k2_)                         \
        LDB_FRAG(b1_[n_][k2_], (c_), 2 + n_, k2_);                                \
    STAGE(A, lda, brow, 1, (T_) + 1, (c_) ^ 1, 1);                                \
    PH_BARRIER(); WAIT_LGKM0();                                                   \
    __builtin_amdgcn_s_setprio(1);                                                \
    MFMA_Q(a_, b1_, 0, 1);                                                        \
    __builtin_amdgcn_s_setprio(0); PH_BARRIER();                                  \
    /* P3: A m4-7 reads; prefetch B-half0(T+2)->buf */                            \
    _Pragma("unroll") for (int m_ = 0; m_ < 4; ++m_)                              \
      _Pragma("unroll") for (int k2_ = 0; k2_ < 2; ++k2_)                         \
        LDA_FRAG(a_[m_][k2_], (c_), 4 + m_, k2_);                                 \
    STAGE(Bm, ldb, bcol, 0, (T_) + 2, (c_), 0);                                   \
    PH_BARRIER(); WAIT_LGKM0();                                                   \
    __builtin_amdgcn_s_setprio(1);                                                \
    MFMA_Q(a_, b0_, 1, 0);                                                        \
    __builtin_amdgcn_s_setprio(0); PH_BARRIER();                                  \
    /* P4: no reads; prefetch A-half0(T+2)->buf; counted vmcnt */                 \
    STAGE(A, lda, brow, 0, (T_) + 2, (c_), 1);                                    \
    PH_BARRIER();                                                                 \
    __builtin_amdgcn_sched_barrier(0);                                            \
    __builtin_amdgcn_s_setprio(1);                                                \
    MFMA_Q(a_, b1_, 1, 1);                                                        \
    __builtin_amdgcn_s_setprio(0);                                                \
    WAIT_VM4(); PH_BARRIER();                                                     \
  } while (0)

template <int EPI>
__global__ __launch_bounds__(512, 2)
void k_gemm8(const bfu* __restrict__ A, int lda,
             const bfu* __restrict__ Bm, int ldb,
             int nkt,                       // K-tiles (per chunk), even
             float* __restrict__ outF, bfu* __restrict__ outB, int ldc,
             int ntc, const float* __restrict__ route,
             const float* __restrict__ bias1) {
  __shared__ __align__(16) bfu lds[65536];  // 128 KiB: [buf][A/B][half][128*64]
  const int tid = (int)threadIdx.x;
  const int w = tid >> 6, l = tid & 63;
  const int wr = w >> 2, wc = w & 3;
  const int rlane = l & 15, chalf = l >> 4;
  const int aBaseByte = rlane * 128 + chalf * 16;
  const int axor = (rlane & 7) << 4;
  const int bhalfSel = wc >> 1;
  const int bInner = (wc & 1) << 13;

  const int nwg = (int)gridDim.x;
  const int bid = (int)blockIdx.x;
  int s = (bid & 7) * (nwg >> 3) + (bid >> 3);   // XCD-contiguous (nwg % 8 == 0)
  int chunk = 0, kOff = 0;
  if (EPI == 2) { chunk = s >> 7; s &= 127; kOff = chunk * (nkt << 6); }
  const int brow = (s / ntc) << 8;
  const int bcol = (s % ntc) << 8;

  f32x4 acc[8][4] = {};
  short8 a_[4][2], b0_[2][2], b1_[2][2];

  // prologue: A0(0) A1(0) B0(0) B1(0) B0(1) A0(1); leave newest 2 units in flight
  STAGE(A, lda, brow, 0, 0, 0, 1);
  STAGE(A, lda, brow, 1, 0, 0, 1);
  STAGE(Bm, ldb, bcol, 0, 0, 0, 0);
  STAGE(Bm, ldb, bcol, 1, 0, 0, 0);
  STAGE(Bm, ldb, bcol, 0, 1, 1, 0);
  STAGE(A, lda, brow, 0, 1, 1, 1);
  WAIT_VM4(); PH_BARRIER();

  for (int it = 0; it < (nkt >> 1); ++it) {
    const int T = it << 1;
    TILE_STEP(T, 0);
    TILE_STEP(T + 1, 1);
  }

  // epilogue
  const int fr = rlane, fq = chalf;
  if (EPI == 1) {
    const int e = bcol >> 8;
    #pragma unroll
    for (int m = 0; m < 8; ++m) {
      const int rl = brow + wr * 128 + m * 16 + fq * 4;
      float rt[4];
      #pragma unroll
      for (int j = 0; j < 4; ++j) rt[j] = route[(size_t)(rl + j) * E_ + e];
      #pragma unroll
      for (int n = 0; n < 4; ++n) {
        const int col = bcol + wc * 64 + n * 16 + fr;
        const float bz = bias1[col];
        #pragma unroll
        for (int j = 0; j < 4; ++j) {
          float v = fmaxf(acc[m][n][j] + bz, 0.f) * rt[j];
          outB[(size_t)(rl + j) * ldc + col] = f2b(v);
        }
      }
    }
  } else {
    #pragma unroll
    for (int m = 0; m < 8; ++m) {
      const int rl = brow + wr * 128 + m * 16 + fq * 4;
      #pragma unroll
      for (int n = 0; n < 4; ++n) {
        const int col = bcol + wc * 64 + n * 16 + fr;
        if (chunk == 0) {
          #pragma unroll
          for (int j = 0; j < 4; ++j)
            outF[(size_t)(rl + j) * ldc + col] = acc[m][n][j];
        } else {
          #pragma unroll
          for (int j = 0; j < 4; ++j)
            outB[(size_t)(rl + j) * ldc + col] = f2b(acc[m][n][j]);
        }
      }
    }
  }
}

// ---------------- reduce: out += P1 + route @ b2 ----------------
__global__ __launch_bounds__(256)
void k_reduce(float* __restrict__ out, const bfu* __restrict__ P1,
              const float* __restrict__ route, const float* __restrict__ b2) {
  __shared__ float sb2[E_ * D_];   // 64 KiB
  for (int i = threadIdx.x; i < E_ * D_; i += 256) sb2[i] = b2[i];
  __syncthreads();
  const int total = (B_ * D_) / 4;
  for (int idx = blockIdx.x * 256 + threadIdx.x; idx < total; idx += gridDim.x * 256) {
    const int b = idx >> 8;            // 256 float4 per row of D=1024
    const int d4 = (idx & 255) * 4;
    float4 o = reinterpret_cast<float4*>(out)[idx];
    ushort4 p = reinterpret_cast<const ushort4*>(P1)[idx];
    o.x += b2f(p.x); o.y += b2f(p.y); o.z += b2f(p.z); o.w += b2f(p.w);
    const float* rr = route + (size_t)b * E_;
    #pragma unroll
    for (int e = 0; e < E_; ++e) {
      const float r = rr[e];
      const float* bb = sb2 + e * D_ + d4;
      o.x = fmaf(r, bb[0], o.x);
      o.y = fmaf(r, bb[1], o.y);
      o.z = fmaf(r, bb[2], o.z);
      o.w = fmaf(r, bb[3], o.w);
    }
    reinterpret_cast<float4*>(out)[idx] = o;
  }
}

// ---------------- launch ----------------
extern "C" void kernel_launch(void* const* d_in, const int* in_sizes, int n_in,
                              void* d_out, int out_size, void* d_ws, size_t ws_size,
                              hipStream_t stream) {
  const float* x    = (const float*)d_in[0];
  const float* cond = (const float*)d_in[1];
  const float* W1   = (const float*)d_in[2];
  const float* b1   = (const float*)d_in[3];
  const float* W2   = (const float*)d_in[4];
  const float* b2   = (const float*)d_in[5];
  const float* Wr1  = (const float*)d_in[6];
  const float* br1  = (const float*)d_in[7];
  const float* Wr2  = (const float*)d_in[8];
  const float* br2  = (const float*)d_in[9];
  float* out = (float*)d_out;

  // ws layout (96.5 MB total; round 1 proved >= ~101 MB available):
  // [Hp 64MB][W2t 8MB][route 0.5MB][W1b 8MB][xb 16MB (= P1 after GEMM1)]
  char* p = (char*)d_ws;
  bfu*   Hp    = (bfu*)p;                 p += (size_t)B_ * EH_ * 2;
  bfu*   W2t   = (bfu*)p;                 p += (size_t)D_ * EH_ * 2;
  float* route = (float*)p;               p += (size_t)B_ * E_ * 4;
  bfu*   W1b   = (bfu*)p;                 p += (size_t)EH_ * D_ * 2;
  bfu*   xb    = (bfu*)p;                 /* B_*D_*2 = 16MB */
  bfu*   P1b   = xb;                      // alias: xb dead after GEMM1

  k_f32_to_bf16<<<(B_ * D_ / 4 + 255) / 256, 256, 0, stream>>>(x, xb, B_ * D_ / 4);
  k_f32_to_bf16<<<(EH_ * D_ / 4 + 255) / 256, 256, 0, stream>>>(W1, W1b, EH_ * D_ / 4);
  k_w2_transpose<<<(E_ * D_ * (H_ / 4) + 255) / 256, 256, 0, stream>>>(W2, W2t);
  k_router<<<B_ / 32, 256, 0, stream>>>(cond, Wr1, br1, Wr2, br2, route);

  // GEMM1: Hp[8192,4096] = relu(xb @ W1b^T + b1) * route   (512 blocks, 2/CU)
  k_gemm8<1><<<dim3((B_ / 256) * (EH_ / 256)), 512, 0, stream>>>(
      xb, D_, W1b, D_, D_ / 64, nullptr, Hp, EH_, EH_ / 256, route, b1);

  // GEMM2: out/P1 = Hp @ W2t^T, split-K x2  (256 blocks, 1/CU)
  k_gemm8<2><<<dim3((B_ / 256) * (D_ / 256) * 2), 512, 0, stream>>>(
      Hp, EH_, W2t, EH_, (EH_ / 64) / 2, out, P1b, D_, D_ / 256, nullptr, nullptr);

  // out += P1 + route @ b2
  k_reduce<<<2048, 256, 0, stream>>>(out, P1b, route, b2);
}